// Round 1
// baseline (759.491 us; speedup 1.0000x reference)
//
#include <hip/hip_runtime.h>
#include <hip/hip_bf16.h>
#include <math.h>

#define NB 32
#define NL 1024
#define ND 128
#define NF 16
#define DT_RANK 8
#define NS 2
#define DCONV 4

// ---------------------------------------------------------------------------
// FiLM conditioning: gb[b][0:128]=gamma, gb[b][128:256]=beta
// gb = silu(gpt_emb @ w1^T + b1) @ w2^T + b2
// ---------------------------------------------------------------------------
__global__ __launch_bounds__(128)
void film_kernel(const float* __restrict__ gpt_emb,
                 const float* __restrict__ w1, const float* __restrict__ b1,
                 const float* __restrict__ w2, const float* __restrict__ b2,
                 float* __restrict__ gb)
{
    int b = blockIdx.x, t = threadIdx.x;
    __shared__ float sg[ND];
    __shared__ float sh[ND];
    sg[t] = gpt_emb[b * ND + t];
    __syncthreads();
    float a = b1[t];
    #pragma unroll 8
    for (int d = 0; d < ND; ++d) a += sg[d] * w1[t * ND + d];
    sh[t] = a / (1.f + expf(-a));   // silu
    __syncthreads();
    float g0 = b2[t], g1 = b2[ND + t];
    #pragma unroll 8
    for (int j = 0; j < ND; ++j) {
        float hv = sh[j];
        g0 += hv * w2[t * ND + j];
        g1 += hv * w2[(ND + t) * ND + j];
    }
    gb[b * 256 + t]      = g0;
    gb[b * 256 + ND + t] = g1;
}

// ---------------------------------------------------------------------------
// Fused RMSNorm -> cross-attention (16 groups) -> FiLM.  One block per (b,l).
// Writes x1 (saved for final residual) and h (input to in_proj GEMM).
// ---------------------------------------------------------------------------
__global__ __launch_bounds__(128)
void fused_pre_kernel(const float* __restrict__ x, const float* __restrict__ fg_emb,
                      const float* __restrict__ norm_w, const float* __restrict__ gb,
                      float* __restrict__ x1_out, float* __restrict__ h_out)
{
    int l = blockIdx.x, b = blockIdx.y, t = threadIdx.x;
    __shared__ float sh[ND];
    __shared__ float sred[2];
    __shared__ float sc[NF];
    long row = ((long)b * NL + l) * ND;
    float v = x[row + t];
    float ss = v * v;
    #pragma unroll
    for (int o = 32; o >= 1; o >>= 1) ss += __shfl_xor(ss, o);
    if ((t & 63) == 0) sred[t >> 6] = ss;
    __syncthreads();
    float mean = (sred[0] + sred[1]) * (1.f / (float)ND);
    float x1v = v * rsqrtf(mean + 1e-5f) * norm_w[t];
    sh[t] = x1v;
    __syncthreads();
    // scores: thread t = f*8 + i
    int f = t >> 3, i = t & 7;
    const float* fgb = fg_emb + ((long)b * NF + f) * ND;
    float p = 0.f;
    #pragma unroll
    for (int e = 0; e < 16; ++e) p += sh[i * 16 + e] * fgb[i * 16 + e];
    p += __shfl_xor(p, 1);
    p += __shfl_xor(p, 2);
    p += __shfl_xor(p, 4);
    if (i == 0) sc[f] = p * 0.08838834764831845f;   // 1/sqrt(128)
    __syncthreads();
    // softmax over 16 groups (redundant per thread, cheap)
    float mx = sc[0];
    #pragma unroll
    for (int ff = 1; ff < NF; ++ff) mx = fmaxf(mx, sc[ff]);
    float wv[NF];
    float wsum = 0.f;
    #pragma unroll
    for (int ff = 0; ff < NF; ++ff) { wv[ff] = expf(sc[ff] - mx); wsum += wv[ff]; }
    float inv = 1.f / wsum;
    float hv = x1v;
    #pragma unroll
    for (int ff = 0; ff < NF; ++ff)
        hv += wv[ff] * inv * fg_emb[((long)b * NF + ff) * ND + t];
    // FiLM
    float gamma = gb[b * 256 + t];
    float beta  = gb[b * 256 + ND + t];
    hv = hv * gamma + beta;
    x1_out[row + t] = x1v;
    h_out[row + t]  = hv;
}

// ---------------------------------------------------------------------------
// Generic fp32 SGEMM: C = A @ B, 128x128 tile, BK=16, 256 threads, 8x8 micro.
// TRANS_B: logical B[k][n] = Bptr[n*ldb + k]   (for W[N][K] row-major)
// EPI==1 : v = isfinite(v)?v:0 ; v += X1[m*128+n]   (out_proj epilogue)
// All dims assumed multiples of the tile (true for this problem).
// ---------------------------------------------------------------------------
template <bool TRANS_B, int EPI>
__global__ __launch_bounds__(256)
void sgemm_kernel(const float* __restrict__ A, const float* __restrict__ B,
                  float* __restrict__ C, const float* __restrict__ X1,
                  int M, int N, int K, int lda, int ldb, int ldc,
                  long strideA, long strideB, long strideC)
{
    __shared__ float As[16][128];
    __shared__ float Bs[16][128];
    int bz = blockIdx.z;
    A += (long)bz * strideA;
    B += (long)bz * strideB;
    C += (long)bz * strideC;
    int m0 = blockIdx.x * 128;
    int n0 = blockIdx.y * 128;
    int tid = threadIdx.x;
    int tx = tid & 15, ty = tid >> 4;
    int lc = tid & 3, lr = tid >> 2;          // transposed-stage mapping
    int ln = tid & 31, lk = tid >> 5;          // direct-stage mapping
    float acc[8][8] = {};

    for (int k0 = 0; k0 < K; k0 += 16) {
        // --- stage A (always transposed to As[k][m]) ---
        #pragma unroll
        for (int h = 0; h < 2; ++h) {
            int m = lr + h * 64;
            float4 v = *(const float4*)&A[(long)(m0 + m) * lda + k0 + 4 * lc];
            As[4 * lc + 0][m] = v.x; As[4 * lc + 1][m] = v.y;
            As[4 * lc + 2][m] = v.z; As[4 * lc + 3][m] = v.w;
        }
        // --- stage B ---
        if (TRANS_B) {
            #pragma unroll
            for (int h = 0; h < 2; ++h) {
                int n = lr + h * 64;
                float4 v = *(const float4*)&B[(long)(n0 + n) * ldb + k0 + 4 * lc];
                Bs[4 * lc + 0][n] = v.x; Bs[4 * lc + 1][n] = v.y;
                Bs[4 * lc + 2][n] = v.z; Bs[4 * lc + 3][n] = v.w;
            }
        } else {
            #pragma unroll
            for (int h = 0; h < 2; ++h) {
                int kk = lk + h * 8;
                float4 v = *(const float4*)&B[(long)(k0 + kk) * ldb + n0 + 4 * ln];
                *(float4*)&Bs[kk][4 * ln] = v;
            }
        }
        __syncthreads();
        #pragma unroll
        for (int kk = 0; kk < 16; ++kk) {
            float a[8], bb[8];
            *(float4*)&a[0]  = *(const float4*)&As[kk][ty * 8];
            *(float4*)&a[4]  = *(const float4*)&As[kk][ty * 8 + 4];
            *(float4*)&bb[0] = *(const float4*)&Bs[kk][tx * 8];
            *(float4*)&bb[4] = *(const float4*)&Bs[kk][tx * 8 + 4];
            #pragma unroll
            for (int i = 0; i < 8; ++i)
                #pragma unroll
                for (int j = 0; j < 8; ++j)
                    acc[i][j] += a[i] * bb[j];
        }
        __syncthreads();
    }

    #pragma unroll
    for (int i = 0; i < 8; ++i) {
        int m = m0 + ty * 8 + i;
        #pragma unroll
        for (int j = 0; j < 8; ++j) {
            int n = n0 + tx * 8 + j;
            float v = acc[i][j];
            if (EPI == 1) {
                if (!isfinite(v)) v = 0.f;
                v += X1[(long)m * ND + n];
            }
            C[(long)m * ldc + n] = v;
        }
    }
}

// ---------------------------------------------------------------------------
// Fused causal depthwise conv1d + SiLU + x_proj + dt_proj + softplus.
// One block per (b,l).  xin = xr[:, :128] (row stride 256).
// Outputs: xs[b,l,d], delta[b,l,d], bc[b,l,4] = {B0,B1,C0,C1}
// ---------------------------------------------------------------------------
__global__ __launch_bounds__(128)
void conv_xproj_kernel(const float* __restrict__ xr,
                       const float* __restrict__ conv_w, const float* __restrict__ conv_b,
                       const float* __restrict__ x_proj_w,
                       const float* __restrict__ dt_proj_w, const float* __restrict__ dt_proj_b,
                       float* __restrict__ xs_out, float* __restrict__ delta_out,
                       float* __restrict__ bc_out)
{
    int l = blockIdx.x, b = blockIdx.y, d = threadIdx.x;
    __shared__ float sxs[ND];
    __shared__ float sdbl[DT_RANK + 2 * NS];
    long base = (long)b * NL + l;
    float acc = conv_b[d];
    #pragma unroll
    for (int k = 0; k < DCONV; ++k) {
        int ll = l + k - (DCONV - 1);
        float xv = (ll >= 0) ? xr[((long)b * NL + ll) * 256 + d] : 0.f;
        acc += conv_w[d * DCONV + k] * xv;
    }
    float xsv = acc / (1.f + expf(-acc));   // silu
    sxs[d] = xsv;
    xs_out[base * ND + d] = xsv;
    __syncthreads();
    int j = d >> 3, i = d & 7;   // j in [0,16), only j<12 active
    if (j < DT_RANK + 2 * NS) {
        const float* wrow = x_proj_w + j * ND;
        float p = 0.f;
        #pragma unroll
        for (int e = 0; e < 16; ++e) p += sxs[i * 16 + e] * wrow[i * 16 + e];
        p += __shfl_xor(p, 1);
        p += __shfl_xor(p, 2);
        p += __shfl_xor(p, 4);
        if (i == 0) sdbl[j] = p;
    }
    __syncthreads();
    float a = dt_proj_b[d];
    #pragma unroll
    for (int r = 0; r < DT_RANK; ++r) a += sdbl[r] * dt_proj_w[d * DT_RANK + r];
    float dl = (a > 20.f) ? a : log1pf(expf(a));   // softplus
    delta_out[base * ND + d] = dl;
    if (d < 4) bc_out[base * 4 + d] = sdbl[DT_RANK + d];
}

// ---------------------------------------------------------------------------
// Selective scan over l, fused with D-skip and silu(res) gate.
// One block per batch, one thread per d; n=2 states in registers.
// ---------------------------------------------------------------------------
__global__ __launch_bounds__(128)
void scan_kernel(const float* __restrict__ delta_p, const float* __restrict__ xs,
                 const float* __restrict__ bc, const float* __restrict__ xr,
                 const float* __restrict__ A_log, const float* __restrict__ D_skip,
                 float* __restrict__ yg)
{
    int b = blockIdx.x, d = threadIdx.x;
    float A0 = -expf(A_log[d * NS + 0]);
    float A1 = -expf(A_log[d * NS + 1]);
    float Dd = D_skip[d];
    float s0 = 0.f, s1 = 0.f;
    const float* dp_p  = delta_p + (long)b * NL * ND + d;
    const float* xs_p  = xs      + (long)b * NL * ND + d;
    const float* res_p = xr      + (long)b * NL * 256 + ND + d;
    const float* bc_p  = bc      + (long)b * NL * 4;
    float* yg_p        = yg      + (long)b * NL * ND + d;
    for (int l = 0; l < NL; ++l) {
        float dp = dp_p[(long)l * ND];
        float xv = xs_p[(long)l * ND];
        float B0 = bc_p[l * 4 + 0], B1 = bc_p[l * 4 + 1];
        float C0 = bc_p[l * 4 + 2], C1 = bc_p[l * 4 + 3];
        s0 = expf(dp * A0) * s0 + dp * B0 * xv;
        s1 = expf(dp * A1) * s1 + dp * B1 * xv;
        float y = s0 * C0 + s1 * C1 + xv * Dd;
        float r = res_p[(long)l * 256];
        yg_p[(long)l * ND] = y * (r / (1.f + expf(-r)));   // y * silu(res)
    }
}

// ---------------------------------------------------------------------------
extern "C" void kernel_launch(void* const* d_in, const int* in_sizes, int n_in,
                              void* d_out, int out_size, void* d_ws, size_t ws_size,
                              hipStream_t stream)
{
    const float* x         = (const float*)d_in[0];
    const float* dis       = (const float*)d_in[1];
    const float* gpt       = (const float*)d_in[2];
    const float* fg        = (const float*)d_in[3];
    const float* norm_w    = (const float*)d_in[4];
    const float* in_proj_w = (const float*)d_in[5];
    const float* conv_w    = (const float*)d_in[6];
    const float* conv_b    = (const float*)d_in[7];
    const float* x_proj_w  = (const float*)d_in[8];
    const float* dt_proj_w = (const float*)d_in[9];
    const float* dt_proj_b = (const float*)d_in[10];
    const float* A_log     = (const float*)d_in[11];
    const float* D_skip    = (const float*)d_in[12];
    const float* out_proj_w= (const float*)d_in[13];
    const float* film_w1   = (const float*)d_in[14];
    const float* film_b1   = (const float*)d_in[15];
    const float* film_w2   = (const float*)d_in[16];
    const float* film_b2   = (const float*)d_in[17];

    float* ws = (float*)d_ws;
    const size_t S = (size_t)NB * NL * ND;   // 4,194,304
    float* x1    = ws;                 // [S]  live to end
    float* h     = ws + S;             // [S]  dead after in_proj
    float* xr    = ws + 2 * S;         // [2S] xin + res
    float* xs    = ws + 4 * S;         // [S]
    float* delta = ws + 5 * S;         // [S]  dead after delta_p GEMM
    float* bc    = ws + 6 * S;         // [NB*NL*4]
    float* gb    = ws + 6 * S + (size_t)NB * NL * 4;  // [NB*256]
    float* delta_p = h;                // reuse (h dead)
    float* yg      = delta;            // reuse (delta dead)

    film_kernel<<<NB, 128, 0, stream>>>(gpt, film_w1, film_b1, film_w2, film_b2, gb);

    fused_pre_kernel<<<dim3(NL, NB), 128, 0, stream>>>(x, fg, norm_w, gb, x1, h);

    // xr = h @ in_proj_w^T   [32768 x 256]
    sgemm_kernel<true, 0><<<dim3(256, 2, 1), 256, 0, stream>>>(
        h, in_proj_w, xr, nullptr,
        NB * NL, 2 * ND, ND, ND, ND, 2 * ND, 0, 0, 0);

    conv_xproj_kernel<<<dim3(NL, NB), 128, 0, stream>>>(
        xr, conv_w, conv_b, x_proj_w, dt_proj_w, dt_proj_b, xs, delta, bc);

    // delta_p[b] = dis[b] @ delta[b]   [1024 x 128], K=1024, batched over 32
    sgemm_kernel<false, 0><<<dim3(8, 1, NB), 256, 0, stream>>>(
        dis, delta, delta_p, nullptr,
        NL, ND, NL, NL, ND, ND,
        (long)NL * NL, (long)NL * ND, (long)NL * ND);

    scan_kernel<<<NB, 128, 0, stream>>>(delta_p, xs, bc, xr, A_log, D_skip, yg);

    // out = finite(yg @ out_proj_w^T) + x1   [32768 x 128]
    sgemm_kernel<true, 1><<<dim3(256, 1, 1), 256, 0, stream>>>(
        yg, out_proj_w, (float*)d_out, x1,
        NB * NL, ND, ND, ND, ND, ND, 0, 0, 0);
}

// Round 2
// 505.850 us; speedup vs baseline: 1.5014x; 1.5014x over previous
//
#include <hip/hip_runtime.h>
#include <hip/hip_bf16.h>
#include <math.h>

#define NB 32
#define NL 1024
#define ND 128
#define NF 16
#define DT_RANK 8
#define NS 2
#define DCONV 4
#define NCHUNK 32
#define CLEN 32   // NL / NCHUNK

// ---------------------------------------------------------------------------
// FiLM conditioning: gb[b][0:128]=gamma, gb[b][128:256]=beta
// ---------------------------------------------------------------------------
__global__ __launch_bounds__(128)
void film_kernel(const float* __restrict__ gpt_emb,
                 const float* __restrict__ w1, const float* __restrict__ b1,
                 const float* __restrict__ w2, const float* __restrict__ b2,
                 float* __restrict__ gb)
{
    int b = blockIdx.x, t = threadIdx.x;
    __shared__ float sg[ND];
    __shared__ float sh[ND];
    sg[t] = gpt_emb[b * ND + t];
    __syncthreads();
    float a = b1[t];
    #pragma unroll 8
    for (int d = 0; d < ND; ++d) a += sg[d] * w1[t * ND + d];
    sh[t] = a / (1.f + expf(-a));   // silu
    __syncthreads();
    float g0 = b2[t], g1 = b2[ND + t];
    #pragma unroll 8
    for (int j = 0; j < ND; ++j) {
        float hv = sh[j];
        g0 += hv * w2[t * ND + j];
        g1 += hv * w2[(ND + t) * ND + j];
    }
    gb[b * 256 + t]      = g0;
    gb[b * 256 + ND + t] = g1;
}

// ---------------------------------------------------------------------------
// Fused RMSNorm -> cross-attention (16 groups) -> FiLM.  One block per (b,l).
// ---------------------------------------------------------------------------
__global__ __launch_bounds__(128)
void fused_pre_kernel(const float* __restrict__ x, const float* __restrict__ fg_emb,
                      const float* __restrict__ norm_w, const float* __restrict__ gb,
                      float* __restrict__ x1_out, float* __restrict__ h_out)
{
    int l = blockIdx.x, b = blockIdx.y, t = threadIdx.x;
    __shared__ float sh[ND];
    __shared__ float sred[2];
    __shared__ float sc[NF];
    long row = ((long)b * NL + l) * ND;
    float v = x[row + t];
    float ss = v * v;
    #pragma unroll
    for (int o = 32; o >= 1; o >>= 1) ss += __shfl_xor(ss, o);
    if ((t & 63) == 0) sred[t >> 6] = ss;
    __syncthreads();
    float mean = (sred[0] + sred[1]) * (1.f / (float)ND);
    float x1v = v * rsqrtf(mean + 1e-5f) * norm_w[t];
    sh[t] = x1v;
    __syncthreads();
    int f = t >> 3, i = t & 7;
    const float* fgb = fg_emb + ((long)b * NF + f) * ND;
    float p = 0.f;
    #pragma unroll
    for (int e = 0; e < 16; ++e) p += sh[i * 16 + e] * fgb[i * 16 + e];
    p += __shfl_xor(p, 1);
    p += __shfl_xor(p, 2);
    p += __shfl_xor(p, 4);
    if (i == 0) sc[f] = p * 0.08838834764831845f;   // 1/sqrt(128)
    __syncthreads();
    float mx = sc[0];
    #pragma unroll
    for (int ff = 1; ff < NF; ++ff) mx = fmaxf(mx, sc[ff]);
    float wv[NF];
    float wsum = 0.f;
    #pragma unroll
    for (int ff = 0; ff < NF; ++ff) { wv[ff] = expf(sc[ff] - mx); wsum += wv[ff]; }
    float inv = 1.f / wsum;
    float hv = x1v;
    #pragma unroll
    for (int ff = 0; ff < NF; ++ff)
        hv += wv[ff] * inv * fg_emb[((long)b * NF + ff) * ND + t];
    float gamma = gb[b * 256 + t];
    float beta  = gb[b * 256 + ND + t];
    hv = hv * gamma + beta;
    x1_out[row + t] = x1v;
    h_out[row + t]  = hv;
}

// ---------------------------------------------------------------------------
// Generic fp32 SGEMM: C = A @ B, 128x128 tile, BK=16, 256 threads, 8x8 micro.
// ---------------------------------------------------------------------------
template <bool TRANS_B, int EPI>
__global__ __launch_bounds__(256)
void sgemm_kernel(const float* __restrict__ A, const float* __restrict__ B,
                  float* __restrict__ C, const float* __restrict__ X1,
                  int M, int N, int K, int lda, int ldb, int ldc,
                  long strideA, long strideB, long strideC)
{
    __shared__ float As[16][128];
    __shared__ float Bs[16][128];
    int bz = blockIdx.z;
    A += (long)bz * strideA;
    B += (long)bz * strideB;
    C += (long)bz * strideC;
    int m0 = blockIdx.x * 128;
    int n0 = blockIdx.y * 128;
    int tid = threadIdx.x;
    int tx = tid & 15, ty = tid >> 4;
    int lc = tid & 3, lr = tid >> 2;
    int ln = tid & 31, lk = tid >> 5;
    float acc[8][8] = {};

    for (int k0 = 0; k0 < K; k0 += 16) {
        #pragma unroll
        for (int h = 0; h < 2; ++h) {
            int m = lr + h * 64;
            float4 v = *(const float4*)&A[(long)(m0 + m) * lda + k0 + 4 * lc];
            As[4 * lc + 0][m] = v.x; As[4 * lc + 1][m] = v.y;
            As[4 * lc + 2][m] = v.z; As[4 * lc + 3][m] = v.w;
        }
        if (TRANS_B) {
            #pragma unroll
            for (int h = 0; h < 2; ++h) {
                int n = lr + h * 64;
                float4 v = *(const float4*)&B[(long)(n0 + n) * ldb + k0 + 4 * lc];
                Bs[4 * lc + 0][n] = v.x; Bs[4 * lc + 1][n] = v.y;
                Bs[4 * lc + 2][n] = v.z; Bs[4 * lc + 3][n] = v.w;
            }
        } else {
            #pragma unroll
            for (int h = 0; h < 2; ++h) {
                int kk = lk + h * 8;
                float4 v = *(const float4*)&B[(long)(k0 + kk) * ldb + n0 + 4 * ln];
                *(float4*)&Bs[kk][4 * ln] = v;
            }
        }
        __syncthreads();
        #pragma unroll
        for (int kk = 0; kk < 16; ++kk) {
            float a[8], bb[8];
            *(float4*)&a[0]  = *(const float4*)&As[kk][ty * 8];
            *(float4*)&a[4]  = *(const float4*)&As[kk][ty * 8 + 4];
            *(float4*)&bb[0] = *(const float4*)&Bs[kk][tx * 8];
            *(float4*)&bb[4] = *(const float4*)&Bs[kk][tx * 8 + 4];
            #pragma unroll
            for (int i = 0; i < 8; ++i)
                #pragma unroll
                for (int j = 0; j < 8; ++j)
                    acc[i][j] += a[i] * bb[j];
        }
        __syncthreads();
    }

    #pragma unroll
    for (int i = 0; i < 8; ++i) {
        int m = m0 + ty * 8 + i;
        #pragma unroll
        for (int j = 0; j < 8; ++j) {
            int n = n0 + tx * 8 + j;
            float v = acc[i][j];
            if (EPI == 1) {
                if (!isfinite(v)) v = 0.f;
                v += X1[(long)m * ND + n];
            }
            C[(long)m * ldc + n] = v;
        }
    }
}

// ---------------------------------------------------------------------------
// Fused causal depthwise conv1d + SiLU + x_proj + dt_proj + softplus.
// ---------------------------------------------------------------------------
__global__ __launch_bounds__(128)
void conv_xproj_kernel(const float* __restrict__ xr,
                       const float* __restrict__ conv_w, const float* __restrict__ conv_b,
                       const float* __restrict__ x_proj_w,
                       const float* __restrict__ dt_proj_w, const float* __restrict__ dt_proj_b,
                       float* __restrict__ xs_out, float* __restrict__ delta_out,
                       float* __restrict__ bc_out)
{
    int l = blockIdx.x, b = blockIdx.y, d = threadIdx.x;
    __shared__ float sxs[ND];
    __shared__ float sdbl[DT_RANK + 2 * NS];
    long base = (long)b * NL + l;
    float acc = conv_b[d];
    #pragma unroll
    for (int k = 0; k < DCONV; ++k) {
        int ll = l + k - (DCONV - 1);
        float xv = (ll >= 0) ? xr[((long)b * NL + ll) * 256 + d] : 0.f;
        acc += conv_w[d * DCONV + k] * xv;
    }
    float xsv = acc / (1.f + expf(-acc));   // silu
    sxs[d] = xsv;
    xs_out[base * ND + d] = xsv;
    __syncthreads();
    int j = d >> 3, i = d & 7;
    if (j < DT_RANK + 2 * NS) {
        const float* wrow = x_proj_w + j * ND;
        float p = 0.f;
        #pragma unroll
        for (int e = 0; e < 16; ++e) p += sxs[i * 16 + e] * wrow[i * 16 + e];
        p += __shfl_xor(p, 1);
        p += __shfl_xor(p, 2);
        p += __shfl_xor(p, 4);
        if (i == 0) sdbl[j] = p;
    }
    __syncthreads();
    float a = dt_proj_b[d];
    #pragma unroll
    for (int r = 0; r < DT_RANK; ++r) a += sdbl[r] * dt_proj_w[d * DT_RANK + r];
    float dl = (a > 20.f) ? a : log1pf(expf(a));   // softplus
    delta_out[base * ND + d] = dl;
    if (d < 4) bc_out[base * 4 + d] = sdbl[DT_RANK + d];
}

// ---------------------------------------------------------------------------
// Chunked parallel scan, 3 phases.  Chain id = (b, d, n); NL split into
// NCHUNK chunks of CLEN.  Summary layout: [b][chunk][n][d]  (d contiguous).
// ---------------------------------------------------------------------------
__global__ __launch_bounds__(128)
void scan_pass1(const float* __restrict__ delta_p, const float* __restrict__ xs,
                const float* __restrict__ bc, const float* __restrict__ A_log,
                float* __restrict__ Pc, float* __restrict__ Sc)
{
    int c = blockIdx.x, b = blockIdx.y, d = threadIdx.x;
    float A0 = -expf(A_log[d * NS + 0]);
    float A1 = -expf(A_log[d * NS + 1]);
    int l0 = c * CLEN;
    const float* dp_p = delta_p + ((long)b * NL + l0) * ND + d;
    const float* xs_p = xs      + ((long)b * NL + l0) * ND + d;
    const float* bc_p = bc      + ((long)b * NL + l0) * 4;
    float p0 = 1.f, p1 = 1.f, s0 = 0.f, s1 = 0.f;
    #pragma unroll 4
    for (int t = 0; t < CLEN; ++t) {
        float dp = dp_p[(long)t * ND];
        float xv = xs_p[(long)t * ND];
        float B0 = bc_p[t * 4 + 0], B1 = bc_p[t * 4 + 1];
        float a0 = expf(dp * A0), a1 = expf(dp * A1);
        float u = dp * xv;
        s0 = a0 * s0 + u * B0;
        s1 = a1 * s1 + u * B1;
        p0 *= a0;
        p1 *= a1;
    }
    long o = ((long)(b * NCHUNK + c) * 2) * ND + d;
    Pc[o] = p0; Pc[o + ND] = p1;
    Sc[o] = s0; Sc[o + ND] = s1;
}

__global__ __launch_bounds__(128)
void scan_combine(const float* __restrict__ Pc, const float* __restrict__ Sc,
                  float* __restrict__ init)
{
    int b = blockIdx.x, d = threadIdx.x;
    float s0 = 0.f, s1 = 0.f;
    #pragma unroll 4
    for (int c = 0; c < NCHUNK; ++c) {
        long o = ((long)(b * NCHUNK + c) * 2) * ND + d;
        init[o] = s0; init[o + ND] = s1;
        s0 = Pc[o] * s0 + Sc[o];
        s1 = Pc[o + ND] * s1 + Sc[o + ND];
    }
}

__global__ __launch_bounds__(128)
void scan_pass3(const float* __restrict__ delta_p, const float* __restrict__ xs,
                const float* __restrict__ bc, const float* __restrict__ xr,
                const float* __restrict__ A_log, const float* __restrict__ D_skip,
                const float* __restrict__ init, float* __restrict__ yg)
{
    int c = blockIdx.x, b = blockIdx.y, d = threadIdx.x;
    float A0 = -expf(A_log[d * NS + 0]);
    float A1 = -expf(A_log[d * NS + 1]);
    float Dd = D_skip[d];
    long o = ((long)(b * NCHUNK + c) * 2) * ND + d;
    float s0 = init[o], s1 = init[o + ND];
    int l0 = c * CLEN;
    const float* dp_p  = delta_p + ((long)b * NL + l0) * ND + d;
    const float* xs_p  = xs      + ((long)b * NL + l0) * ND + d;
    const float* bc_p  = bc      + ((long)b * NL + l0) * 4;
    const float* res_p = xr      + ((long)b * NL + l0) * 256 + ND + d;
    float* yg_p        = yg      + ((long)b * NL + l0) * ND + d;
    #pragma unroll 4
    for (int t = 0; t < CLEN; ++t) {
        float dp = dp_p[(long)t * ND];
        float xv = xs_p[(long)t * ND];
        float B0 = bc_p[t * 4 + 0], B1 = bc_p[t * 4 + 1];
        float C0 = bc_p[t * 4 + 2], C1 = bc_p[t * 4 + 3];
        float a0 = expf(dp * A0), a1 = expf(dp * A1);
        float u = dp * xv;
        s0 = a0 * s0 + u * B0;
        s1 = a1 * s1 + u * B1;
        float y = s0 * C0 + s1 * C1 + xv * Dd;
        float r = res_p[(long)t * 256];
        yg_p[(long)t * ND] = y * (r / (1.f + expf(-r)));   // y * silu(res)
    }
}

// ---------------------------------------------------------------------------
extern "C" void kernel_launch(void* const* d_in, const int* in_sizes, int n_in,
                              void* d_out, int out_size, void* d_ws, size_t ws_size,
                              hipStream_t stream)
{
    const float* x         = (const float*)d_in[0];
    const float* dis       = (const float*)d_in[1];
    const float* gpt       = (const float*)d_in[2];
    const float* fg        = (const float*)d_in[3];
    const float* norm_w    = (const float*)d_in[4];
    const float* in_proj_w = (const float*)d_in[5];
    const float* conv_w    = (const float*)d_in[6];
    const float* conv_b    = (const float*)d_in[7];
    const float* x_proj_w  = (const float*)d_in[8];
    const float* dt_proj_w = (const float*)d_in[9];
    const float* dt_proj_b = (const float*)d_in[10];
    const float* A_log     = (const float*)d_in[11];
    const float* D_skip    = (const float*)d_in[12];
    const float* out_proj_w= (const float*)d_in[13];
    const float* film_w1   = (const float*)d_in[14];
    const float* film_b1   = (const float*)d_in[15];
    const float* film_w2   = (const float*)d_in[16];
    const float* film_b2   = (const float*)d_in[17];

    float* ws = (float*)d_ws;
    const size_t S = (size_t)NB * NL * ND;   // 4,194,304
    float* x1    = ws;                 // [S]  live to end
    float* h     = ws + S;             // [S]  dead after in_proj
    float* xr    = ws + 2 * S;         // [2S] xin + res
    float* xs    = ws + 4 * S;         // [S]
    float* delta = ws + 5 * S;         // [S]  dead after delta_p GEMM
    float* bc    = ws + 6 * S;         // [NB*NL*4]
    float* gb    = ws + 6 * S + (size_t)NB * NL * 4;           // [NB*256]
    float* scr   = gb + (size_t)NB * 256;
    const size_t CS = (size_t)NB * NCHUNK * 2 * ND;            // 262144
    float* Pc    = scr;            // [CS]
    float* Sc    = scr + CS;       // [CS]
    float* initb = scr + 2 * CS;   // [CS]
    float* delta_p = h;                // reuse (h dead)
    float* yg      = delta;            // reuse (delta dead)

    film_kernel<<<NB, 128, 0, stream>>>(gpt, film_w1, film_b1, film_w2, film_b2, gb);

    fused_pre_kernel<<<dim3(NL, NB), 128, 0, stream>>>(x, fg, norm_w, gb, x1, h);

    // xr = h @ in_proj_w^T   [32768 x 256]
    sgemm_kernel<true, 0><<<dim3(256, 2, 1), 256, 0, stream>>>(
        h, in_proj_w, xr, nullptr,
        NB * NL, 2 * ND, ND, ND, ND, 2 * ND, 0, 0, 0);

    conv_xproj_kernel<<<dim3(NL, NB), 128, 0, stream>>>(
        xr, conv_w, conv_b, x_proj_w, dt_proj_w, dt_proj_b, xs, delta, bc);

    // delta_p[b] = dis[b] @ delta[b]   [1024 x 128], K=1024, batched over 32
    sgemm_kernel<false, 0><<<dim3(8, 1, NB), 256, 0, stream>>>(
        dis, delta, delta_p, nullptr,
        NL, ND, NL, NL, ND, ND,
        (long)NL * NL, (long)NL * ND, (long)NL * ND);

    // chunked selective scan (3 phases) fused with D-skip + silu(res) gate
    scan_pass1<<<dim3(NCHUNK, NB), 128, 0, stream>>>(delta_p, xs, bc, A_log, Pc, Sc);
    scan_combine<<<NB, 128, 0, stream>>>(Pc, Sc, initb);
    scan_pass3<<<dim3(NCHUNK, NB), 128, 0, stream>>>(
        delta_p, xs, bc, xr, A_log, D_skip, initb, yg);

    // out = finite(yg @ out_proj_w^T) + x1   [32768 x 128]
    sgemm_kernel<true, 1><<<dim3(256, 1, 1), 256, 0, stream>>>(
        yg, out_proj_w, (float*)d_out, x1,
        NB * NL, ND, ND, ND, ND, ND, 0, 0, 0);
}

// Round 3
// 382.423 us; speedup vs baseline: 1.9860x; 1.3227x over previous
//
#include <hip/hip_runtime.h>
#include <hip/hip_bf16.h>
#include <math.h>

#define NB 32
#define NL 1024
#define ND 128
#define NF 16
#define DT_RANK 8
#define NS 2
#define DCONV 4
#define NCHUNK 32
#define CLEN 32   // NL / NCHUNK

typedef __attribute__((ext_vector_type(8))) short bf16x8;
typedef __attribute__((ext_vector_type(4))) float f32x4;

__device__ inline unsigned short f2bf(float x) {
    unsigned u = __float_as_uint(x);
    return (unsigned short)((u + 0x7fffu + ((u >> 16) & 1u)) >> 16);   // RNE
}
__device__ inline unsigned pk2(float a, float b) {
    return (unsigned)f2bf(a) | ((unsigned)f2bf(b) << 16);
}

// ---------------------------------------------------------------------------
// FiLM conditioning: gb[b][0:128]=gamma, gb[b][128:256]=beta
// ---------------------------------------------------------------------------
__global__ __launch_bounds__(128)
void film_kernel(const float* __restrict__ gpt_emb,
                 const float* __restrict__ w1, const float* __restrict__ b1,
                 const float* __restrict__ w2, const float* __restrict__ b2,
                 float* __restrict__ gb)
{
    int b = blockIdx.x, t = threadIdx.x;
    __shared__ float sg[ND];
    __shared__ float sh[ND];
    sg[t] = gpt_emb[b * ND + t];
    __syncthreads();
    float a = b1[t];
    #pragma unroll 8
    for (int d = 0; d < ND; ++d) a += sg[d] * w1[t * ND + d];
    sh[t] = a / (1.f + expf(-a));   // silu
    __syncthreads();
    float g0 = b2[t], g1 = b2[ND + t];
    #pragma unroll 8
    for (int j = 0; j < ND; ++j) {
        float hv = sh[j];
        g0 += hv * w2[t * ND + j];
        g1 += hv * w2[(ND + t) * ND + j];
    }
    gb[b * 256 + t]      = g0;
    gb[b * 256 + ND + t] = g1;
}

// ---------------------------------------------------------------------------
// Fused RMSNorm -> cross-attention (16 groups) -> FiLM.  One block per (b,l).
// ---------------------------------------------------------------------------
__global__ __launch_bounds__(128)
void fused_pre_kernel(const float* __restrict__ x, const float* __restrict__ fg_emb,
                      const float* __restrict__ norm_w, const float* __restrict__ gb,
                      float* __restrict__ x1_out, float* __restrict__ h_out)
{
    int l = blockIdx.x, b = blockIdx.y, t = threadIdx.x;
    __shared__ float sh[ND];
    __shared__ float sred[2];
    __shared__ float sc[NF];
    long row = ((long)b * NL + l) * ND;
    float v = x[row + t];
    float ss = v * v;
    #pragma unroll
    for (int o = 32; o >= 1; o >>= 1) ss += __shfl_xor(ss, o);
    if ((t & 63) == 0) sred[t >> 6] = ss;
    __syncthreads();
    float mean = (sred[0] + sred[1]) * (1.f / (float)ND);
    float x1v = v * rsqrtf(mean + 1e-5f) * norm_w[t];
    sh[t] = x1v;
    __syncthreads();
    int f = t >> 3, i = t & 7;
    const float* fgb = fg_emb + ((long)b * NF + f) * ND;
    float p = 0.f;
    #pragma unroll
    for (int e = 0; e < 16; ++e) p += sh[i * 16 + e] * fgb[i * 16 + e];
    p += __shfl_xor(p, 1);
    p += __shfl_xor(p, 2);
    p += __shfl_xor(p, 4);
    if (i == 0) sc[f] = p * 0.08838834764831845f;   // 1/sqrt(128)
    __syncthreads();
    float mx = sc[0];
    #pragma unroll
    for (int ff = 1; ff < NF; ++ff) mx = fmaxf(mx, sc[ff]);
    float wv[NF];
    float wsum = 0.f;
    #pragma unroll
    for (int ff = 0; ff < NF; ++ff) { wv[ff] = expf(sc[ff] - mx); wsum += wv[ff]; }
    float inv = 1.f / wsum;
    float hv = x1v;
    #pragma unroll
    for (int ff = 0; ff < NF; ++ff)
        hv += wv[ff] * inv * fg_emb[((long)b * NF + ff) * ND + t];
    float gamma = gb[b * 256 + t];
    float beta  = gb[b * 256 + ND + t];
    hv = hv * gamma + beta;
    x1_out[row + t] = x1v;
    h_out[row + t]  = hv;
}

// ---------------------------------------------------------------------------
// Weight GEMM (MFMA bf16): C[M][N] = A[M][128] @ W[N][128]^T, BM=64, BN=128.
// Whole K=128 staged once.  EPI==1: finite-filter + add X1 (out_proj).
// grid (M/64, N/128), 256 threads = 4 waves, each wave 16 rows x 128 cols.
// ---------------------------------------------------------------------------
template <int EPI>
__global__ __launch_bounds__(256)
void wgemm_kernel(const float* __restrict__ A, const float* __restrict__ W,
                  float* __restrict__ C, const float* __restrict__ X1, int ldc)
{
    __shared__ __align__(16) unsigned short As[64 * 136];   // row stride 272 B
    __shared__ __align__(16) unsigned short Ws[128 * 136];
    int m0 = blockIdx.x * 64, n0 = blockIdx.y * 128;
    int t = threadIdx.x;
    int lane = t & 63, w = t >> 6, lrow = lane & 15, lgrp = lane >> 4;
    {   // stage A: 64 rows x 128 k fp32 -> bf16
        int r = t >> 2, c = t & 3;
        const float* Ap = A + ((long)(m0 + r)) * 128;
        #pragma unroll
        for (int q = 0; q < 4; ++q) {
            int col = c * 8 + q * 32;
            float4 v0 = *(const float4*)(Ap + col);
            float4 v1 = *(const float4*)(Ap + col + 4);
            int4 pv;
            pv.x = pk2(v0.x, v0.y); pv.y = pk2(v0.z, v0.w);
            pv.z = pk2(v1.x, v1.y); pv.w = pk2(v1.z, v1.w);
            *(int4*)((char*)As + r * 272 + col * 2) = pv;
        }
    }
    {   // stage W: 128 rows x 128 k fp32 -> bf16
        int r = t >> 1, h2 = t & 1;
        const float* Wp = W + ((long)(n0 + r)) * 128;
        #pragma unroll
        for (int p = 0; p < 8; ++p) {
            int col = h2 * 8 + p * 16;
            float4 v0 = *(const float4*)(Wp + col);
            float4 v1 = *(const float4*)(Wp + col + 4);
            int4 pv;
            pv.x = pk2(v0.x, v0.y); pv.y = pk2(v0.z, v0.w);
            pv.z = pk2(v1.x, v1.y); pv.w = pk2(v1.z, v1.w);
            *(int4*)((char*)Ws + r * 272 + col * 2) = pv;
        }
    }
    __syncthreads();
    const char* Ar = (const char*)As + (w * 16 + lrow) * 272 + lgrp * 16;
    const char* Wr = (const char*)Ws + lrow * 272 + lgrp * 16;
    bf16x8 a[4];
    #pragma unroll
    for (int c4 = 0; c4 < 4; ++c4) a[c4] = *(const bf16x8*)(Ar + c4 * 64);
    f32x4 acc[8];
    #pragma unroll
    for (int i = 0; i < 8; ++i) acc[i] = (f32x4){0.f, 0.f, 0.f, 0.f};
    #pragma unroll
    for (int nb = 0; nb < 8; ++nb) {
        #pragma unroll
        for (int c4 = 0; c4 < 4; ++c4) {
            bf16x8 bb = *(const bf16x8*)(Wr + nb * 16 * 272 + c4 * 64);
            acc[nb] = __builtin_amdgcn_mfma_f32_16x16x32_bf16(a[c4], bb, acc[nb], 0, 0, 0);
        }
    }
    #pragma unroll
    for (int nb = 0; nb < 8; ++nb) {
        #pragma unroll
        for (int r = 0; r < 4; ++r) {
            long m = m0 + w * 16 + lgrp * 4 + r;
            int n = n0 + nb * 16 + lrow;
            float v = acc[nb][r];
            if (EPI == 1) {
                if (!isfinite(v)) v = 0.f;
                v += X1[m * ND + n];
            }
            C[m * ldc + n] = v;
        }
    }
}

// ---------------------------------------------------------------------------
// Fused causal depthwise conv1d + SiLU + x_proj + dt_proj + softplus.
// delta written directly as bf16 (consumed only by transpose+dpgemm).
// ---------------------------------------------------------------------------
__global__ __launch_bounds__(128)
void conv_xproj_kernel(const float* __restrict__ xr,
                       const float* __restrict__ conv_w, const float* __restrict__ conv_b,
                       const float* __restrict__ x_proj_w,
                       const float* __restrict__ dt_proj_w, const float* __restrict__ dt_proj_b,
                       float* __restrict__ xs_out, unsigned short* __restrict__ delta_out,
                       float* __restrict__ bc_out)
{
    int l = blockIdx.x, b = blockIdx.y, d = threadIdx.x;
    __shared__ float sxs[ND];
    __shared__ float sdbl[DT_RANK + 2 * NS];
    long base = (long)b * NL + l;
    float acc = conv_b[d];
    #pragma unroll
    for (int k = 0; k < DCONV; ++k) {
        int ll = l + k - (DCONV - 1);
        float xv = (ll >= 0) ? xr[((long)b * NL + ll) * 256 + d] : 0.f;
        acc += conv_w[d * DCONV + k] * xv;
    }
    float xsv = acc / (1.f + expf(-acc));   // silu
    sxs[d] = xsv;
    xs_out[base * ND + d] = xsv;
    __syncthreads();
    int j = d >> 3, i = d & 7;
    if (j < DT_RANK + 2 * NS) {
        const float* wrow = x_proj_w + j * ND;
        float p = 0.f;
        #pragma unroll
        for (int e = 0; e < 16; ++e) p += sxs[i * 16 + e] * wrow[i * 16 + e];
        p += __shfl_xor(p, 1);
        p += __shfl_xor(p, 2);
        p += __shfl_xor(p, 4);
        if (i == 0) sdbl[j] = p;
    }
    __syncthreads();
    float a = dt_proj_b[d];
    #pragma unroll
    for (int r = 0; r < DT_RANK; ++r) a += sdbl[r] * dt_proj_w[d * DT_RANK + r];
    float dl = (a > 20.f) ? a : log1pf(expf(a));   // softplus
    delta_out[base * ND + d] = f2bf(dl);
    if (d < 4) bc_out[base * 4 + d] = sdbl[DT_RANK + d];
}

// ---------------------------------------------------------------------------
// Transpose delta (bf16): [b][l][d] -> [b][d][l].  64x64 tiles via LDS.
// ---------------------------------------------------------------------------
__global__ __launch_bounds__(256)
void transpose_kernel(const unsigned short* __restrict__ din,
                      unsigned short* __restrict__ dout)
{
    __shared__ __align__(16) unsigned short T[64 * 72];   // pad 8 -> 144B rows
    int b = blockIdx.z, d0 = blockIdx.y * 64, l0 = blockIdx.x * 64;
    int t = threadIdx.x;
    int lr = t >> 2, c = t & 3;
    const unsigned short* src = din + ((long)b * NL + l0 + lr) * ND + d0;
    #pragma unroll
    for (int j = 0; j < 2; ++j) {
        int ds_ = (c + j * 4) * 8;
        *(int4*)&T[lr * 72 + ds_] = *(const int4*)(src + ds_);
    }
    __syncthreads();
    int dr = t >> 2;
    unsigned short* dst = dout + ((long)b * ND + d0 + dr) * NL + l0;
    #pragma unroll
    for (int j = 0; j < 2; ++j) {
        int ls = (c + j * 4) * 8;
        unsigned short tmp[8];
        #pragma unroll
        for (int e = 0; e < 8; ++e) tmp[e] = T[(ls + e) * 72 + dr];
        *(int4*)(dst + ls) = *(int4*)tmp;
    }
}

// ---------------------------------------------------------------------------
// delta_p GEMM (MFMA bf16): dp[b] = dis[b][1024x1024] @ delta[b][1024x128].
// A fp32 converted on the fly; B read pre-transposed bf16 (dbt [b][d][l]).
// BM=64, BN=128, BK=64; grid (16, NB); 256 threads = 4 waves.
// ---------------------------------------------------------------------------
__global__ __launch_bounds__(256)
void dpgemm_kernel(const float* __restrict__ dis, const unsigned short* __restrict__ dbt,
                   float* __restrict__ dp)
{
    __shared__ __align__(16) unsigned short As[64 * 72];    // row stride 144 B
    __shared__ __align__(16) unsigned short Bs[128 * 72];
    int b = blockIdx.y, m0 = blockIdx.x * 64;
    int t = threadIdx.x;
    int lane = t & 63, w = t >> 6, lrow = lane & 15, lgrp = lane >> 4;
    int ar = t >> 2, ac = t & 3;
    int br = t >> 1, bh = t & 1;
    const float* Ag = dis + ((long)b * NL + m0 + ar) * NL;
    const unsigned short* Bg = dbt + ((long)b * ND + br) * NL;
    f32x4 acc[8];
    #pragma unroll
    for (int i = 0; i < 8; ++i) acc[i] = (f32x4){0.f, 0.f, 0.f, 0.f};
    const char* Ar = (const char*)As + (w * 16 + lrow) * 144 + lgrp * 16;
    const char* Br = (const char*)Bs + lrow * 144 + lgrp * 16;

    for (int k0 = 0; k0 < NL; k0 += 64) {
        #pragma unroll
        for (int q = 0; q < 4; ++q) {
            float4 v = *(const float4*)(Ag + k0 + ac * 4 + q * 16);
            unsigned long long pv = (unsigned long long)pk2(v.x, v.y)
                                  | ((unsigned long long)pk2(v.z, v.w) << 32);
            *(unsigned long long*)((char*)As + ar * 144 + ac * 8 + q * 32) = pv;
        }
        #pragma unroll
        for (int j = 0; j < 4; ++j) {
            int slot = bh * 4 + j;
            *(int4*)((char*)Bs + br * 144 + slot * 16) =
                *(const int4*)(Bg + k0 + slot * 8);
        }
        __syncthreads();
        bf16x8 a0 = *(const bf16x8*)(Ar);
        bf16x8 a1 = *(const bf16x8*)(Ar + 64);
        #pragma unroll
        for (int nb = 0; nb < 8; ++nb) {
            bf16x8 b0 = *(const bf16x8*)(Br + nb * 16 * 144);
            bf16x8 b1 = *(const bf16x8*)(Br + nb * 16 * 144 + 64);
            acc[nb] = __builtin_amdgcn_mfma_f32_16x16x32_bf16(a0, b0, acc[nb], 0, 0, 0);
            acc[nb] = __builtin_amdgcn_mfma_f32_16x16x32_bf16(a1, b1, acc[nb], 0, 0, 0);
        }
        __syncthreads();
    }
    float* Cp = dp + ((long)b * NL + m0 + w * 16 + lgrp * 4) * ND + lrow;
    #pragma unroll
    for (int nb = 0; nb < 8; ++nb)
        #pragma unroll
        for (int r = 0; r < 4; ++r)
            Cp[(long)r * ND + nb * 16] = acc[nb][r];
}

// ---------------------------------------------------------------------------
// Chunked parallel scan, 3 phases.
// ---------------------------------------------------------------------------
__global__ __launch_bounds__(128)
void scan_pass1(const float* __restrict__ delta_p, const float* __restrict__ xs,
                const float* __restrict__ bc, const float* __restrict__ A_log,
                float* __restrict__ Pc, float* __restrict__ Sc)
{
    int c = blockIdx.x, b = blockIdx.y, d = threadIdx.x;
    float A0 = -expf(A_log[d * NS + 0]);
    float A1 = -expf(A_log[d * NS + 1]);
    int l0 = c * CLEN;
    const float* dp_p = delta_p + ((long)b * NL + l0) * ND + d;
    const float* xs_p = xs      + ((long)b * NL + l0) * ND + d;
    const float* bc_p = bc      + ((long)b * NL + l0) * 4;
    float p0 = 1.f, p1 = 1.f, s0 = 0.f, s1 = 0.f;
    #pragma unroll 4
    for (int t = 0; t < CLEN; ++t) {
        float dp = dp_p[(long)t * ND];
        float xv = xs_p[(long)t * ND];
        float B0 = bc_p[t * 4 + 0], B1 = bc_p[t * 4 + 1];
        float a0 = expf(dp * A0), a1 = expf(dp * A1);
        float u = dp * xv;
        s0 = a0 * s0 + u * B0;
        s1 = a1 * s1 + u * B1;
        p0 *= a0;
        p1 *= a1;
    }
    long o = ((long)(b * NCHUNK + c) * 2) * ND + d;
    Pc[o] = p0; Pc[o + ND] = p1;
    Sc[o] = s0; Sc[o + ND] = s1;
}

__global__ __launch_bounds__(128)
void scan_combine(const float* __restrict__ Pc, const float* __restrict__ Sc,
                  float* __restrict__ init)
{
    int b = blockIdx.x, d = threadIdx.x;
    float s0 = 0.f, s1 = 0.f;
    #pragma unroll 4
    for (int c = 0; c < NCHUNK; ++c) {
        long o = ((long)(b * NCHUNK + c) * 2) * ND + d;
        init[o] = s0; init[o + ND] = s1;
        s0 = Pc[o] * s0 + Sc[o];
        s1 = Pc[o + ND] * s1 + Sc[o + ND];
    }
}

__global__ __launch_bounds__(128)
void scan_pass3(const float* __restrict__ delta_p, const float* __restrict__ xs,
                const float* __restrict__ bc, const float* __restrict__ xr,
                const float* __restrict__ A_log, const float* __restrict__ D_skip,
                const float* __restrict__ init, float* __restrict__ yg)
{
    int c = blockIdx.x, b = blockIdx.y, d = threadIdx.x;
    float A0 = -expf(A_log[d * NS + 0]);
    float A1 = -expf(A_log[d * NS + 1]);
    float Dd = D_skip[d];
    long o = ((long)(b * NCHUNK + c) * 2) * ND + d;
    float s0 = init[o], s1 = init[o + ND];
    int l0 = c * CLEN;
    const float* dp_p  = delta_p + ((long)b * NL + l0) * ND + d;
    const float* xs_p  = xs      + ((long)b * NL + l0) * ND + d;
    const float* bc_p  = bc      + ((long)b * NL + l0) * 4;
    const float* res_p = xr      + ((long)b * NL + l0) * 256 + ND + d;
    float* yg_p        = yg      + ((long)b * NL + l0) * ND + d;
    #pragma unroll 4
    for (int t = 0; t < CLEN; ++t) {
        float dp = dp_p[(long)t * ND];
        float xv = xs_p[(long)t * ND];
        float B0 = bc_p[t * 4 + 0], B1 = bc_p[t * 4 + 1];
        float C0 = bc_p[t * 4 + 2], C1 = bc_p[t * 4 + 3];
        float a0 = expf(dp * A0), a1 = expf(dp * A1);
        float u = dp * xv;
        s0 = a0 * s0 + u * B0;
        s1 = a1 * s1 + u * B1;
        float y = s0 * C0 + s1 * C1 + xv * Dd;
        float r = res_p[(long)t * 256];
        yg_p[(long)t * ND] = y * (r / (1.f + expf(-r)));   // y * silu(res)
    }
}

// ---------------------------------------------------------------------------
extern "C" void kernel_launch(void* const* d_in, const int* in_sizes, int n_in,
                              void* d_out, int out_size, void* d_ws, size_t ws_size,
                              hipStream_t stream)
{
    const float* x         = (const float*)d_in[0];
    const float* dis       = (const float*)d_in[1];
    const float* gpt       = (const float*)d_in[2];
    const float* fg        = (const float*)d_in[3];
    const float* norm_w    = (const float*)d_in[4];
    const float* in_proj_w = (const float*)d_in[5];
    const float* conv_w    = (const float*)d_in[6];
    const float* conv_b    = (const float*)d_in[7];
    const float* x_proj_w  = (const float*)d_in[8];
    const float* dt_proj_w = (const float*)d_in[9];
    const float* dt_proj_b = (const float*)d_in[10];
    const float* A_log     = (const float*)d_in[11];
    const float* D_skip    = (const float*)d_in[12];
    const float* out_proj_w= (const float*)d_in[13];
    const float* film_w1   = (const float*)d_in[14];
    const float* film_b1   = (const float*)d_in[15];
    const float* film_w2   = (const float*)d_in[16];
    const float* film_b2   = (const float*)d_in[17];

    float* ws = (float*)d_ws;
    const size_t S = (size_t)NB * NL * ND;   // 4,194,304
    float* x1    = ws;                 // [S]  live to end
    float* h     = ws + S;             // [S]  dead after in_proj -> delta_p
    float* xr    = ws + 2 * S;         // [2S] xin + res
    float* xs    = ws + 4 * S;         // [S]
    // region [5S, 6S): first delta_bf16 [S bf16] + dbt [S bf16]; later yg [S fp32]
    unsigned short* delta_b = (unsigned short*)(ws + 5 * S);
    unsigned short* dbt     = delta_b + S;
    float* yg    = ws + 5 * S;
    float* bc    = ws + 6 * S;         // [NB*NL*4]
    float* gb    = ws + 6 * S + (size_t)NB * NL * 4;           // [NB*256]
    float* scr   = gb + (size_t)NB * 256;
    const size_t CS = (size_t)NB * NCHUNK * 2 * ND;            // 262144
    float* Pc    = scr;
    float* Sc    = scr + CS;
    float* initb = scr + 2 * CS;
    float* delta_p = h;                // reuse (h dead after in_proj)

    film_kernel<<<NB, 128, 0, stream>>>(gpt, film_w1, film_b1, film_w2, film_b2, gb);

    fused_pre_kernel<<<dim3(NL, NB), 128, 0, stream>>>(x, fg, norm_w, gb, x1, h);

    // xr = h @ in_proj_w^T   [32768 x 256]
    wgemm_kernel<0><<<dim3(512, 2), 256, 0, stream>>>(h, in_proj_w, xr, nullptr, 256);

    conv_xproj_kernel<<<dim3(NL, NB), 128, 0, stream>>>(
        xr, conv_w, conv_b, x_proj_w, dt_proj_w, dt_proj_b, xs, delta_b, bc);

    // dbt[b][d][l] = delta[b][l][d]
    transpose_kernel<<<dim3(16, 2, NB), 256, 0, stream>>>(delta_b, dbt);

    // delta_p[b] = dis[b] @ delta[b]
    dpgemm_kernel<<<dim3(16, NB), 256, 0, stream>>>(dis, dbt, delta_p);

    // chunked selective scan (3 phases) fused with D-skip + silu(res) gate
    scan_pass1<<<dim3(NCHUNK, NB), 128, 0, stream>>>(delta_p, xs, bc, A_log, Pc, Sc);
    scan_combine<<<NB, 128, 0, stream>>>(Pc, Sc, initb);
    scan_pass3<<<dim3(NCHUNK, NB), 128, 0, stream>>>(
        delta_p, xs, bc, xr, A_log, D_skip, initb, yg);

    // out = finite(yg @ out_proj_w^T) + x1   [32768 x 128]
    wgemm_kernel<1><<<dim3(512, 1), 256, 0, stream>>>(yg, out_proj_w, (float*)d_out, x1, 128);
}